// Round 10
// baseline (30.476 us; speedup 1.0000x reference)
//
#include <hip/hip_runtime.h>

// EvenLayer (neural BP even/check layer), MI355X — R10.
//
// Structure: mask = kron(eye(256), ones(16,16)-eye(16)) => block-diag 16x16.
// Numeric core (R8, passed absmax 0.0): log2-domain matvec with hardware
// v_log_f32, epilogue even=±exp2f(a2), n=(1+even)+eps, d=(1-even)+eps,
// out=__logf(n/d). Quantization at 1.0f reproduces ref's zeros exactly.
//
// R10 probe: NO LDS, NO barrier. Each thread reads its 16x16 W block directly
// from global (64x16B; 4 lanes/wave per row -> L1 broadcast; 256 KB total
// device-wide -> L2-hot). Removes the per-block staging burst + __syncthreads
// phase alignment that R2-R9 all shared. Diag-zero stays compile-time (full
// unroll) so the fma chain is bit-identical to R8. If this is flat too, the
// dur_us floor is harness overhead + mandatory HBM traffic => roofline.

constexpr int M_CHECKS = 256;
constexpr int DC = 16;
constexpr int NEURONS = M_CHECKS * DC;   // 4096
constexpr int BATCH = 1024;
constexpr float EPS = 1e-8f;

constexpr int CB = 16;    // checks per block
constexpr int BB = 16;    // batches per block

__global__ __launch_bounds__(256, 4) void even_layer_kernel(
    const float* __restrict__ x,      // [BATCH, NEURONS]
    const float* __restrict__ w,      // [NEURONS, NEURONS], only block-diag used
    float* __restrict__ out)          // [BATCH, NEURONS]
{
    const int tid = (int)threadIdx.x;
    const int cb  = (int)blockIdx.x & 15;   // check-block 0..15
    const int bb  = (int)blockIdx.x >> 4;   // batch-block 0..63

    const int bi = tid >> 4;                // local batch 0..15
    const int ci = tid & 15;                // local check 0..15 (fast => coalesced)
    const int b  = bb * BB + bi;
    const int c  = cb * CB + ci;

    // ---- x loads (coalesced 64B/lane) ----
    const float* xp = x + (size_t)b * NEURONS + (size_t)(c * DC);
    float4 xv[4];
    #pragma unroll
    for (int k = 0; k < 4; ++k) xv[k] = *(const float4*)(xp + 4 * k);

    // ---- log2 pre-pass (static indexing, frees xv) ----
    float la2[DC];
    int sbits = 0;
    #pragma unroll
    for (int j = 0; j < DC; ++j) {
        const float xj = ((const float*)xv)[j];
        la2[j] = __log2f(fabsf(xj) + EPS);
        if (xj < 0.0f) sbits |= (1 << j);
    }
    const int sall = __popc(sbits) & 1;

    // ---- matvec: W rows direct from global; diag zeroed compile-time ----
    const float* wp = w + (size_t)(c * DC) * NEURONS + (size_t)(c * DC);

    float a2[DC];
    #pragma unroll
    for (int i = 0; i < DC; ++i) a2[i] = 0.0f;

    #pragma unroll
    for (int j = 0; j < DC; ++j) {
        const float lj = la2[j];
        const float* wr = wp + (size_t)j * NEURONS;
        float4 w0 = *(const float4*)(wr);
        float4 w1 = *(const float4*)(wr + 4);
        float4 w2 = *(const float4*)(wr + 8);
        float4 w3 = *(const float4*)(wr + 12);
        // zero W[j][j] (mask); j is compile-time constant under full unroll
        if ((j >> 2) == 0) {
            if ((j & 3) == 0) w0.x = 0.0f; else if ((j & 3) == 1) w0.y = 0.0f;
            else if ((j & 3) == 2) w0.z = 0.0f; else w0.w = 0.0f;
        } else if ((j >> 2) == 1) {
            if ((j & 3) == 0) w1.x = 0.0f; else if ((j & 3) == 1) w1.y = 0.0f;
            else if ((j & 3) == 2) w1.z = 0.0f; else w1.w = 0.0f;
        } else if ((j >> 2) == 2) {
            if ((j & 3) == 0) w2.x = 0.0f; else if ((j & 3) == 1) w2.y = 0.0f;
            else if ((j & 3) == 2) w2.z = 0.0f; else w2.w = 0.0f;
        } else {
            if ((j & 3) == 0) w3.x = 0.0f; else if ((j & 3) == 1) w3.y = 0.0f;
            else if ((j & 3) == 2) w3.z = 0.0f; else w3.w = 0.0f;
        }
        a2[0]  = fmaf(lj, w0.x, a2[0]);
        a2[1]  = fmaf(lj, w0.y, a2[1]);
        a2[2]  = fmaf(lj, w0.z, a2[2]);
        a2[3]  = fmaf(lj, w0.w, a2[3]);
        a2[4]  = fmaf(lj, w1.x, a2[4]);
        a2[5]  = fmaf(lj, w1.y, a2[5]);
        a2[6]  = fmaf(lj, w1.z, a2[6]);
        a2[7]  = fmaf(lj, w1.w, a2[7]);
        a2[8]  = fmaf(lj, w2.x, a2[8]);
        a2[9]  = fmaf(lj, w2.y, a2[9]);
        a2[10] = fmaf(lj, w2.z, a2[10]);
        a2[11] = fmaf(lj, w2.w, a2[11]);
        a2[12] = fmaf(lj, w3.x, a2[12]);
        a2[13] = fmaf(lj, w3.y, a2[13]);
        a2[14] = fmaf(lj, w3.z, a2[14]);
        a2[15] = fmaf(lj, w3.w, a2[15]);
    }

    // ---- branchless epilogue (R8 verbatim) ----
    float* op = out + (size_t)b * NEURONS + (size_t)(c * DC);

    #pragma unroll
    for (int k = 0; k < 4; ++k) {
        float4 o;
        #pragma unroll
        for (int e = 0; e < 4; ++e) {
            const int i = 4 * k + e;
            const float m = exp2f(a2[i]);                   // native v_exp_f32
            const int par = sall ^ ((sbits >> i) & 1);
            const float even = par ? -m : m;
            const float n = (1.0f + even) + EPS;            // ref op order
            const float d = (1.0f - even) + EPS;
            const float q = n / d;                          // IEEE f32 div
            const float r = __logf(q);                      // v_log_f32 * ln2
            if (e == 0) o.x = r; else if (e == 1) o.y = r;
            else if (e == 2) o.z = r; else o.w = r;
        }
        *(float4*)(op + 4 * k) = o;
    }
}

extern "C" void kernel_launch(void* const* d_in, const int* in_sizes, int n_in,
                              void* d_out, int out_size, void* d_ws, size_t ws_size,
                              hipStream_t stream) {
    const float* x = (const float*)d_in[0];          // [1024, 4096]
    const float* w = (const float*)d_in[1];          // [4096, 4096] even_weights
    // d_in[2] = w_even2odd_mask: structure hard-coded, never read
    float* out = (float*)d_out;                      // [1024, 4096] f32

    dim3 grid((BATCH / BB) * (M_CHECKS / CB));       // 64 * 16 = 1024 blocks
    dim3 block(256);
    hipLaunchKernelGGL(even_layer_kernel, grid, block, 0, stream, x, w, out);
}